// Round 1
// baseline (652.381 us; speedup 1.0000x reference)
//
#include <hip/hip_runtime.h>
#include <cstdint>
#include <cstddef>

#define BB 4
#define HQ 32
#define HKV 8
#define DD 128
#define S_PAST 8192
#define HID 4096
#define KVLEN 8193                 // S_PAST + 1
#define TOKEN_BUDGET 256
#define INIT_BUDGET 4
#define RECENT_BUDGET 256
#define ALLOW_LO INIT_BUDGET       // 4
#define ALLOW_HI (KVLEN - 1 - RECENT_BUDGET)  // 7936 inclusive
#define RECENT_LO (KVLEN - RECENT_BUDGET)     // 7937
#define SSTRIDE 8224

// ws layout in floats
#define OFF_Q 0                       // [B][HQ*D]   = 16384
#define OFF_K 16384                   // [B][HKV*D]  = 4096
#define OFF_V 20480                   // [B][HKV*D]  = 4096
#define OFF_S 24576                   // [B][HQ][SSTRIDE] = 1052672
#define OFF_A (OFF_S + BB*HQ*SSTRIDE) // [B][HQ*D]   = 16384

__device__ __forceinline__ unsigned fkey(float f) {
    unsigned u = __float_as_uint(f);
    return (u & 0x80000000u) ? ~u : (u | 0x80000000u); // monotone order-preserving map
}

// ---------------- Kernel 1: fused QKV GEMV (K-split, atomic accumulate) ----------------
__global__ __launch_bounds__(256) void k_qkv(const float* __restrict__ hidden,
                                             const float* __restrict__ wq,
                                             const float* __restrict__ wk,
                                             const float* __restrict__ wv,
                                             float* __restrict__ ws) {
    __shared__ float hs[BB][512];
    const int tid = threadIdx.x;
    const int i0 = blockIdx.y * 512;
    for (int idx = tid; idx < BB * 512; idx += 256) {
        int b = idx >> 9, ii = idx & 511;
        hs[b][ii] = hidden[b * HID + i0 + ii];
    }
    __syncthreads();
    const int c = blockIdx.x * 256 + tid;   // 0..6143, block fully inside one region
    const float* w; int stride; float* dst; int bstride;
    if (c < 4096)      { w = wq + c;          stride = HQ*DD;  dst = ws + OFF_Q + c;          bstride = HQ*DD;  }
    else if (c < 5120) { w = wk + (c - 4096); stride = HKV*DD; dst = ws + OFF_K + (c - 4096); bstride = HKV*DD; }
    else               { w = wv + (c - 5120); stride = HKV*DD; dst = ws + OFF_V + (c - 5120); bstride = HKV*DD; }
    w += (size_t)i0 * stride;
    float a0 = 0.f, a1 = 0.f, a2 = 0.f, a3 = 0.f;
    #pragma unroll 8
    for (int ii = 0; ii < 512; ++ii) {
        float wval = *w; w += stride;
        a0 = fmaf(hs[0][ii], wval, a0);
        a1 = fmaf(hs[1][ii], wval, a1);
        a2 = fmaf(hs[2][ii], wval, a2);
        a3 = fmaf(hs[3][ii], wval, a3);
    }
    atomicAdd(dst + 0 * bstride, a0);
    atomicAdd(dst + 1 * bstride, a1);
    atomicAdd(dst + 2 * bstride, a2);
    atomicAdd(dst + 3 * bstride, a3);
}

// ---------------- Kernel 2: RoPE on q and k_new (in-place in ws) ----------------
__global__ __launch_bounds__(128) void k_rope(float* __restrict__ ws,
                                              const float* __restrict__ cosp,
                                              const float* __restrict__ sinp) {
    const int blk = blockIdx.x;
    const int b = blk / (HQ + HKV);
    const int h = blk % (HQ + HKV);
    float* ptr = (h < HQ) ? (ws + OFF_Q + b * HQ * DD + h * DD)
                          : (ws + OFF_K + b * HKV * DD + (h - HQ) * DD);
    const int d = threadIdx.x;
    float x  = ptr[d];
    float xp = ptr[d ^ 64];
    float c = cosp[b * DD + d], s = sinp[b * DD + d];
    float rot = (d < 64) ? -xp : xp;
    float val = fmaf(x, c, rot * s);
    __syncthreads();           // all reads complete before any write
    ptr[d] = val;
}

// ---------------- Kernel 3: scores = q . K / sqrt(D) for all 8193 positions ----------------
__global__ __launch_bounds__(256) void k_scores(const float* __restrict__ past_key,
                                                float* __restrict__ ws) {
    const int tid = threadIdx.x;
    const int blk = blockIdx.x;           // B*HKV*33
    const int chunk = blk % 33;
    const int bkv = blk / 33;
    const int b = bkv >> 3, kv = bkv & 7;
    __shared__ float qs[4][DD];
    for (int idx = tid; idx < 4 * DD; idx += 256) {
        int g = idx >> 7, d = idx & 127;
        qs[g][d] = ws[OFF_Q + b * HQ * DD + (kv * 4 + g) * DD + d];
    }
    __syncthreads();
    const int j = chunk * 256 + tid;
    if (j > S_PAST) return;
    const float4* krow = (j < S_PAST)
        ? (const float4*)(past_key + ((size_t)(b * HKV + kv) * S_PAST + j) * DD)
        : (const float4*)(ws + OFF_K + b * HKV * DD + kv * DD);
    float a0 = 0.f, a1 = 0.f, a2 = 0.f, a3 = 0.f;
    #pragma unroll 8
    for (int d4 = 0; d4 < 32; ++d4) {
        float4 k4 = krow[d4];
        float4 q0 = ((const float4*)qs[0])[d4];
        float4 q1 = ((const float4*)qs[1])[d4];
        float4 q2 = ((const float4*)qs[2])[d4];
        float4 q3 = ((const float4*)qs[3])[d4];
        a0 += k4.x*q0.x + k4.y*q0.y + k4.z*q0.z + k4.w*q0.w;
        a1 += k4.x*q1.x + k4.y*q1.y + k4.z*q1.z + k4.w*q1.w;
        a2 += k4.x*q2.x + k4.y*q2.y + k4.z*q2.z + k4.w*q2.w;
        a3 += k4.x*q3.x + k4.y*q3.y + k4.z*q3.z + k4.w*q3.w;
    }
    const float scale = 0.08838834764831845f; // 1/sqrt(128)
    float* srow = ws + OFF_S + (size_t)(b * HQ + kv * 4) * SSTRIDE + j;
    srow[0 * SSTRIDE] = a0 * scale;
    srow[1 * SSTRIDE] = a1 * scale;
    srow[2 * SSTRIDE] = a2 * scale;
    srow[3 * SSTRIDE] = a3 * scale;
}

// ---------------- Kernel 4: per-(b,h) exact top-k + softmax + A@V ----------------
__global__ __launch_bounds__(256) void k_attn(const float* __restrict__ past_value,
                                              float* __restrict__ ws) {
    const int tid = threadIdx.x;
    const int blk = blockIdx.x;          // B*HQ = 128
    const int b = blk >> 5, h = blk & 31, kv = h >> 2;
    const float* srow = ws + OFF_S + (size_t)(b * HQ + h) * SSTRIDE;

    __shared__ int   hist[256];
    __shared__ int   sbuf[256];
    __shared__ float redm[4];
    __shared__ int   s_bucket, s_above, s_jcut, s_cnt;
    __shared__ float s_sum;
    __shared__ int   list[520];
    __shared__ float wl[520];
    __shared__ float red[8][DD];

    // ---- row max (top-1 is always kept, so this is a valid softmax max) ----
    float m = -3.4e38f;
    for (int j = tid; j < KVLEN; j += 256) m = fmaxf(m, srow[j]);
    #pragma unroll
    for (int off = 32; off; off >>= 1) m = fmaxf(m, __shfl_xor(m, off, 64));
    if ((tid & 63) == 0) redm[tid >> 6] = m;
    __syncthreads();
    m = fmaxf(fmaxf(redm[0], redm[1]), fmaxf(redm[2], redm[3]));

    // ---- 4-pass radix select: key of the 256th largest in [ALLOW_LO, ALLOW_HI] ----
    unsigned prefix = 0; int K = TOKEN_BUDGET; int E = 0;
    for (int pass = 0; pass < 4; ++pass) {
        const int shift = 24 - 8 * pass;
        hist[tid] = 0;
        __syncthreads();
        for (int j = ALLOW_LO + tid; j <= ALLOW_HI; j += 256) {
            unsigned u = fkey(srow[j]);
            unsigned hi = u >> shift;
            if ((hi >> 8) == prefix) atomicAdd(&hist[hi & 255], 1);
        }
        __syncthreads();
        sbuf[tid] = hist[tid];
        __syncthreads();
        for (int dd = 1; dd < 256; dd <<= 1) {           // suffix sum
            int t = (tid + dd < 256) ? sbuf[tid + dd] : 0;
            __syncthreads();
            sbuf[tid] += t;
            __syncthreads();
        }
        if (sbuf[tid] >= K && (tid == 255 || sbuf[tid + 1] < K)) {
            s_bucket = tid;
            s_above  = (tid == 255) ? 0 : sbuf[tid + 1];
        }
        __syncthreads();
        K -= s_above;
        prefix = (prefix << 8) | (unsigned)s_bucket;
        if (pass == 3) E = hist[s_bucket];
        __syncthreads();
    }
    const unsigned tkey = prefix;
    const int T = K;    // number of key==tkey elements to keep (lowest indices first)

    if (tid == 0) {
        s_cnt = 0; s_sum = 0.f;
        if (E > T) {    // rare exact-tie path: find index of T-th equal element
            int cnt = 0, jc = -1;
            for (int j = ALLOW_LO; j <= ALLOW_HI; ++j) {
                if (fkey(srow[j]) == tkey) { if (++cnt == T) { jc = j; break; } }
            }
            s_jcut = jc;
        } else {
            s_jcut = ALLOW_HI;   // keep all equals
        }
    }
    __syncthreads();
    const int jcut = s_jcut;

    // ---- compact kept set + softmax weights ----
    for (int j = tid; j < KVLEN; j += 256) {
        float s = srow[j];
        bool keep;
        if (j < INIT_BUDGET || j >= RECENT_LO) keep = true;
        else {
            unsigned u = fkey(s);
            keep = (u > tkey) || (u == tkey && j <= jcut);
        }
        if (keep) {
            float e = expf(s - m);
            int p = atomicAdd(&s_cnt, 1);
            list[p] = j; wl[p] = e;
            atomicAdd(&s_sum, e);
        }
    }
    __syncthreads();
    const int cnt = s_cnt;           // = 516
    const float inv = 1.0f / s_sum;

    // ---- gathered A@V: 8 groups of 32 lanes, each group strides over kept rows ----
    const int g = tid >> 5, dq = tid & 31;
    float ax = 0.f, ay = 0.f, az = 0.f, aw = 0.f;
    for (int e = g; e < cnt; e += 8) {
        int j = list[e]; float w = wl[e];
        const float4* vrow = (j < S_PAST)
            ? (const float4*)(past_value + ((size_t)(b * HKV + kv) * S_PAST + j) * DD)
            : (const float4*)(ws + OFF_V + b * HKV * DD + kv * DD);
        float4 v4 = vrow[dq];
        ax = fmaf(w, v4.x, ax); ay = fmaf(w, v4.y, ay);
        az = fmaf(w, v4.z, az); aw = fmaf(w, v4.w, aw);
    }
    red[g][dq * 4 + 0] = ax; red[g][dq * 4 + 1] = ay;
    red[g][dq * 4 + 2] = az; red[g][dq * 4 + 3] = aw;
    __syncthreads();
    if (tid < DD) {
        float s = 0.f;
        #pragma unroll
        for (int gg = 0; gg < 8; ++gg) s += red[gg][tid];
        ws[OFF_A + b * HQ * DD + h * DD + tid] = s * inv;
    }
}

// ---------------- Kernel 5: output GEMV over wo (K-split, atomic accumulate) ----------------
__global__ __launch_bounds__(256) void k_out(const float* __restrict__ ws,
                                             const float* __restrict__ wo,
                                             float* __restrict__ out) {
    __shared__ float a[BB][256];
    const int tid = threadIdx.x;
    const int i0 = blockIdx.y * 256;
    for (int idx = tid; idx < BB * 256; idx += 256) {
        int b = idx >> 8, ii = idx & 255;
        a[b][ii] = ws[OFF_A + b * HQ * DD + i0 + ii];
    }
    __syncthreads();
    const int c = blockIdx.x * 256 + tid;
    const float* w = wo + (size_t)i0 * HID + c;
    float a0 = 0.f, a1 = 0.f, a2 = 0.f, a3 = 0.f;
    #pragma unroll 8
    for (int ii = 0; ii < 256; ++ii) {
        float wval = *w; w += HID;
        a0 = fmaf(a[0][ii], wval, a0);
        a1 = fmaf(a[1][ii], wval, a1);
        a2 = fmaf(a[2][ii], wval, a2);
        a3 = fmaf(a[3][ii], wval, a3);
    }
    atomicAdd(&out[0 * HID + c], a0);
    atomicAdd(&out[1 * HID + c], a1);
    atomicAdd(&out[2 * HID + c], a2);
    atomicAdd(&out[3 * HID + c], a3);
}

extern "C" void kernel_launch(void* const* d_in, const int* in_sizes, int n_in,
                              void* d_out, int out_size, void* d_ws, size_t ws_size,
                              hipStream_t stream) {
    const float* hidden = (const float*)d_in[0];
    const float* cosp   = (const float*)d_in[1];
    const float* sinp   = (const float*)d_in[2];
    const float* pk     = (const float*)d_in[3];
    const float* pv     = (const float*)d_in[4];
    const float* wq     = (const float*)d_in[5];
    const float* wk     = (const float*)d_in[6];
    const float* wv     = (const float*)d_in[7];
    const float* wo     = (const float*)d_in[8];
    float* out = (float*)d_out;
    float* ws  = (float*)d_ws;

    // zero atomic-accumulation targets (ws/out are poisoned 0xAA before each launch)
    hipMemsetAsync(out, 0, (size_t)BB * HID * sizeof(float), stream);
    hipMemsetAsync(ws, 0, (size_t)(OFF_V + BB * HKV * DD) * sizeof(float), stream);

    k_qkv  <<<dim3(24, 8),  256, 0, stream>>>(hidden, wq, wk, wv, ws);
    k_rope <<<BB * (HQ + HKV), 128, 0, stream>>>(ws, cosp, sinp);
    k_scores<<<BB * HKV * 33, 256, 0, stream>>>(pk, ws);
    k_attn <<<BB * HQ, 256, 0, stream>>>(pv, ws);
    k_out  <<<dim3(16, 16), 256, 0, stream>>>(ws, wo, out);
}

// Round 2
// 525.136 us; speedup vs baseline: 1.2423x; 1.2423x over previous
//
#include <hip/hip_runtime.h>
#include <cstdint>
#include <cstddef>

#define BB 4
#define HQ 32
#define HKV 8
#define DD 128
#define S_PAST 8192
#define HID 4096
#define KVLEN 8193                 // S_PAST + 1
#define TOKEN_BUDGET 256
#define INIT_BUDGET 4
#define RECENT_BUDGET 256
#define ALLOW_LO INIT_BUDGET       // 4
#define ALLOW_HI (KVLEN - 1 - RECENT_BUDGET)  // 7936 inclusive
#define RECENT_LO (KVLEN - RECENT_BUDGET)     // 7937
#define SSTRIDE 8224

// ws layout in floats (~8.5 MB total — partials region is reused by both GEMVs)
#define OFF_Q 0                       // [B][HQ*D]   = 16384
#define OFF_K 16384                   // [B][HKV*D]  = 4096
#define OFF_V 20480                   // [B][HKV*D]  = 4096
#define OFF_S 24576                   // [B][HQ][SSTRIDE] = 1052672
#define OFF_A (OFF_S + BB*HQ*SSTRIDE) // [B][HQ*D]   = 16384  -> 1077248
#define OFF_P (OFF_A + BB*HQ*DD)      // partials: max(32*4*6144, 64*4*4096)=1048576

#define NCH1 32   // K-split chunks for qkv GEMV (rows/chunk = 128)
#define NCH2 64   // K-split chunks for out GEMV (rows/chunk = 64)

__device__ __forceinline__ unsigned fkey(float f) {
    unsigned u = __float_as_uint(f);
    return (u & 0x80000000u) ? ~u : (u | 0x80000000u); // monotone order-preserving map
}

// ---------------- Kernel 1: fused QKV GEMV, float4 columns, partial-sum stores ----------------
// grid (6, NCH1): bx covers 1024 cols (4/thread); by covers 128 rows.
__global__ __launch_bounds__(256) void k_qkv(const float* __restrict__ hidden,
                                             const float* __restrict__ wq,
                                             const float* __restrict__ wk,
                                             const float* __restrict__ wv,
                                             float* __restrict__ wsp) {
    __shared__ float hs[BB][128];
    const int tid = threadIdx.x;
    const int bx = blockIdx.x, ch = blockIdx.y;
    const int i0 = ch * 128;
    for (int idx = tid; idx < BB * 128; idx += 256) {
        int b = idx >> 7, ii = idx & 127;
        hs[b][ii] = hidden[b * HID + i0 + ii];
    }
    __syncthreads();
    const int c4 = bx * 1024 + tid * 4;            // global col, block stays in one region
    const float* w; int stride; int local;
    if (bx < 4)       { w = wq; stride = HQ  * DD; local = c4;        }
    else if (bx == 4) { w = wk; stride = HKV * DD; local = c4 - 4096; }
    else              { w = wv; stride = HKV * DD; local = c4 - 5120; }
    float4 a0 = {0,0,0,0}, a1 = {0,0,0,0}, a2 = {0,0,0,0}, a3 = {0,0,0,0};
    #pragma unroll 8
    for (int ii = 0; ii < 128; ++ii) {
        float4 w4 = *(const float4*)(w + (size_t)(i0 + ii) * stride + local);
        float h0 = hs[0][ii], h1 = hs[1][ii], h2 = hs[2][ii], h3 = hs[3][ii];
        a0.x = fmaf(h0, w4.x, a0.x); a0.y = fmaf(h0, w4.y, a0.y); a0.z = fmaf(h0, w4.z, a0.z); a0.w = fmaf(h0, w4.w, a0.w);
        a1.x = fmaf(h1, w4.x, a1.x); a1.y = fmaf(h1, w4.y, a1.y); a1.z = fmaf(h1, w4.z, a1.z); a1.w = fmaf(h1, w4.w, a1.w);
        a2.x = fmaf(h2, w4.x, a2.x); a2.y = fmaf(h2, w4.y, a2.y); a2.z = fmaf(h2, w4.z, a2.z); a2.w = fmaf(h2, w4.w, a2.w);
        a3.x = fmaf(h3, w4.x, a3.x); a3.y = fmaf(h3, w4.y, a3.y); a3.z = fmaf(h3, w4.z, a3.z); a3.w = fmaf(h3, w4.w, a3.w);
    }
    const int cq = bx * 256 + tid;  // c4/4
    ((float4*)(wsp + (size_t)(ch * 4 + 0) * 6144))[cq] = a0;
    ((float4*)(wsp + (size_t)(ch * 4 + 1) * 6144))[cq] = a1;
    ((float4*)(wsp + (size_t)(ch * 4 + 2) * 6144))[cq] = a2;
    ((float4*)(wsp + (size_t)(ch * 4 + 3) * 6144))[cq] = a3;
}

// ---------------- Kernel 2: reduce qkv partials + fused RoPE ----------------
// grid 24 x 256 threads; thread owns one output column c; rope pair c^64 is in-block.
__global__ __launch_bounds__(256) void k_qkv_red(const float* __restrict__ wsp,
                                                 const float* __restrict__ cosp,
                                                 const float* __restrict__ sinp,
                                                 float* __restrict__ ws) {
    __shared__ float sh[BB][256];
    const int tid = threadIdx.x;
    const int c = blockIdx.x * 256 + tid;
    float s[BB] = {0.f, 0.f, 0.f, 0.f};
    #pragma unroll 4
    for (int ch = 0; ch < NCH1; ++ch) {
        #pragma unroll
        for (int b = 0; b < BB; ++b) s[b] += wsp[(size_t)(ch * 4 + b) * 6144 + c];
    }
    #pragma unroll
    for (int b = 0; b < BB; ++b) sh[b][tid] = s[b];
    __syncthreads();
    const int d = c & 127;
    #pragma unroll
    for (int b = 0; b < BB; ++b) {
        float val = s[b];
        if (c < 5120) {  // rope applies to q and k_new only
            float part = sh[b][tid ^ 64];
            float rot = (d < 64) ? -part : part;
            val = fmaf(val, cosp[b * DD + d], rot * sinp[b * DD + d]);
        }
        float* dst;
        if (c < 4096)      dst = ws + OFF_Q + b * HQ * DD + c;
        else if (c < 5120) dst = ws + OFF_K + b * HKV * DD + (c - 4096);
        else               dst = ws + OFF_V + b * HKV * DD + (c - 5120);
        *dst = val;
    }
}

// ---------------- Kernel 3: scores, 32 lanes cooperate per K-row ----------------
// grid B*HKV*16; group g of 8 per block; lane l loads float4 #l of the row.
__global__ __launch_bounds__(256) void k_scores(const float* __restrict__ past_key,
                                                float* __restrict__ ws) {
    const int tid = threadIdx.x, blk = blockIdx.x;
    const int chunk = blk & 15, bkv = blk >> 4;
    const int b = bkv >> 3, kv = bkv & 7;
    const int l = tid & 31, g = tid >> 5;
    const float4* qbase = (const float4*)(ws + OFF_Q + (size_t)b * HQ * DD + (size_t)kv * 4 * DD);
    const float4 q0 = qbase[l], q1 = qbase[32 + l], q2 = qbase[64 + l], q3 = qbase[96 + l];
    const float* kbase = past_key + (size_t)(b * HKV + kv) * S_PAST * DD;
    const float4* knew = (const float4*)(ws + OFF_V - 4096 /*OFF_K*/ + b * HKV * DD + kv * DD);
    float* srow = ws + OFF_S + (size_t)(b * HQ + kv * 4) * SSTRIDE;
    const float scale = 0.08838834764831845f; // 1/sqrt(128)
    const int rows = (chunk == 15) ? 513 : 512;
    #pragma unroll 4
    for (int r = g; r < rows; r += 8) {
        const int j = chunk * 512 + r;
        const float4 k4 = (j < S_PAST) ? ((const float4*)(kbase + (size_t)j * DD))[l] : knew[l];
        float p0 = k4.x*q0.x + k4.y*q0.y + k4.z*q0.z + k4.w*q0.w;
        float p1 = k4.x*q1.x + k4.y*q1.y + k4.z*q1.z + k4.w*q1.w;
        float p2 = k4.x*q2.x + k4.y*q2.y + k4.z*q2.z + k4.w*q2.w;
        float p3 = k4.x*q3.x + k4.y*q3.y + k4.z*q3.z + k4.w*q3.w;
        #pragma unroll
        for (int off = 16; off; off >>= 1) {
            p0 += __shfl_xor(p0, off);
            p1 += __shfl_xor(p1, off);
            p2 += __shfl_xor(p2, off);
            p3 += __shfl_xor(p3, off);
        }
        if (l == 0) {
            srow[0 * SSTRIDE + j] = p0 * scale;
            srow[1 * SSTRIDE + j] = p1 * scale;
            srow[2 * SSTRIDE + j] = p2 * scale;
            srow[3 * SSTRIDE + j] = p3 * scale;
        }
    }
}

// ---------------- Kernel 4: per-(b,h) exact top-k + softmax + A@V (unchanged) ----------------
__global__ __launch_bounds__(256) void k_attn(const float* __restrict__ past_value,
                                              float* __restrict__ ws) {
    const int tid = threadIdx.x;
    const int blk = blockIdx.x;          // B*HQ = 128
    const int b = blk >> 5, h = blk & 31, kv = h >> 2;
    const float* srow = ws + OFF_S + (size_t)(b * HQ + h) * SSTRIDE;

    __shared__ int   hist[256];
    __shared__ int   sbuf[256];
    __shared__ float redm[4];
    __shared__ int   s_bucket, s_above, s_jcut, s_cnt;
    __shared__ float s_sum;
    __shared__ int   list[520];
    __shared__ float wl[520];
    __shared__ float red[8][DD];

    // ---- row max (top-1 is always kept, so this is a valid softmax max) ----
    float m = -3.4e38f;
    for (int j = tid; j < KVLEN; j += 256) m = fmaxf(m, srow[j]);
    #pragma unroll
    for (int off = 32; off; off >>= 1) m = fmaxf(m, __shfl_xor(m, off, 64));
    if ((tid & 63) == 0) redm[tid >> 6] = m;
    __syncthreads();
    m = fmaxf(fmaxf(redm[0], redm[1]), fmaxf(redm[2], redm[3]));

    // ---- 4-pass radix select: key of the 256th largest in [ALLOW_LO, ALLOW_HI] ----
    unsigned prefix = 0; int K = TOKEN_BUDGET; int E = 0;
    for (int pass = 0; pass < 4; ++pass) {
        const int shift = 24 - 8 * pass;
        hist[tid] = 0;
        __syncthreads();
        for (int j = ALLOW_LO + tid; j <= ALLOW_HI; j += 256) {
            unsigned u = fkey(srow[j]);
            unsigned hi = u >> shift;
            if ((hi >> 8) == prefix) atomicAdd(&hist[hi & 255], 1);
        }
        __syncthreads();
        sbuf[tid] = hist[tid];
        __syncthreads();
        for (int dd = 1; dd < 256; dd <<= 1) {           // suffix sum
            int t = (tid + dd < 256) ? sbuf[tid + dd] : 0;
            __syncthreads();
            sbuf[tid] += t;
            __syncthreads();
        }
        if (sbuf[tid] >= K && (tid == 255 || sbuf[tid + 1] < K)) {
            s_bucket = tid;
            s_above  = (tid == 255) ? 0 : sbuf[tid + 1];
        }
        __syncthreads();
        K -= s_above;
        prefix = (prefix << 8) | (unsigned)s_bucket;
        if (pass == 3) E = hist[s_bucket];
        __syncthreads();
    }
    const unsigned tkey = prefix;
    const int T = K;    // number of key==tkey elements to keep (lowest indices first)

    if (tid == 0) {
        s_cnt = 0; s_sum = 0.f;
        if (E > T) {    // rare exact-tie path: find index of T-th equal element
            int cnt = 0, jc = -1;
            for (int j = ALLOW_LO; j <= ALLOW_HI; ++j) {
                if (fkey(srow[j]) == tkey) { if (++cnt == T) { jc = j; break; } }
            }
            s_jcut = jc;
        } else {
            s_jcut = ALLOW_HI;   // keep all equals
        }
    }
    __syncthreads();
    const int jcut = s_jcut;

    // ---- compact kept set + softmax weights ----
    for (int j = tid; j < KVLEN; j += 256) {
        float s = srow[j];
        bool keep;
        if (j < INIT_BUDGET || j >= RECENT_LO) keep = true;
        else {
            unsigned u = fkey(s);
            keep = (u > tkey) || (u == tkey && j <= jcut);
        }
        if (keep) {
            float e = expf(s - m);
            int p = atomicAdd(&s_cnt, 1);
            list[p] = j; wl[p] = e;
            atomicAdd(&s_sum, e);
        }
    }
    __syncthreads();
    const int cnt = s_cnt;           // = 516
    const float inv = 1.0f / s_sum;

    // ---- gathered A@V: 8 groups of 32 lanes, each group strides over kept rows ----
    const int g = tid >> 5, dq = tid & 31;
    float ax = 0.f, ay = 0.f, az = 0.f, aw = 0.f;
    for (int e = g; e < cnt; e += 8) {
        int j = list[e]; float w = wl[e];
        const float4* vrow = (j < S_PAST)
            ? (const float4*)(past_value + ((size_t)(b * HKV + kv) * S_PAST + j) * DD)
            : (const float4*)(ws + OFF_V + b * HKV * DD + kv * DD);
        float4 v4 = vrow[dq];
        ax = fmaf(w, v4.x, ax); ay = fmaf(w, v4.y, ay);
        az = fmaf(w, v4.z, az); aw = fmaf(w, v4.w, aw);
    }
    red[g][dq * 4 + 0] = ax; red[g][dq * 4 + 1] = ay;
    red[g][dq * 4 + 2] = az; red[g][dq * 4 + 3] = aw;
    __syncthreads();
    if (tid < DD) {
        float s = 0.f;
        #pragma unroll
        for (int gg = 0; gg < 8; ++gg) s += red[gg][tid];
        ws[OFF_A + b * HQ * DD + h * DD + tid] = s * inv;
    }
}

// ---------------- Kernel 5: output GEMV, float4 columns, partial-sum stores ----------------
// grid (4, NCH2): bx covers 1024 cols (4/thread); by covers 64 rows.
__global__ __launch_bounds__(256) void k_out(const float* __restrict__ ws,
                                             const float* __restrict__ wo,
                                             float* __restrict__ wsp) {
    __shared__ float a[BB][64];
    const int tid = threadIdx.x;
    const int bx = blockIdx.x, ch = blockIdx.y;
    const int i0 = ch * 64;
    if (tid < BB * 64) {
        int b = tid >> 6, ii = tid & 63;
        a[b][ii] = ws[OFF_A + b * HQ * DD + i0 + ii];
    }
    __syncthreads();
    const int c4 = bx * 1024 + tid * 4;
    float4 a0 = {0,0,0,0}, a1 = {0,0,0,0}, a2 = {0,0,0,0}, a3 = {0,0,0,0};
    #pragma unroll 8
    for (int ii = 0; ii < 64; ++ii) {
        float4 w4 = *(const float4*)(wo + (size_t)(i0 + ii) * HID + c4);
        float h0 = a[0][ii], h1 = a[1][ii], h2 = a[2][ii], h3 = a[3][ii];
        a0.x = fmaf(h0, w4.x, a0.x); a0.y = fmaf(h0, w4.y, a0.y); a0.z = fmaf(h0, w4.z, a0.z); a0.w = fmaf(h0, w4.w, a0.w);
        a1.x = fmaf(h1, w4.x, a1.x); a1.y = fmaf(h1, w4.y, a1.y); a1.z = fmaf(h1, w4.z, a1.z); a1.w = fmaf(h1, w4.w, a1.w);
        a2.x = fmaf(h2, w4.x, a2.x); a2.y = fmaf(h2, w4.y, a2.y); a2.z = fmaf(h2, w4.z, a2.z); a2.w = fmaf(h2, w4.w, a2.w);
        a3.x = fmaf(h3, w4.x, a3.x); a3.y = fmaf(h3, w4.y, a3.y); a3.z = fmaf(h3, w4.z, a3.z); a3.w = fmaf(h3, w4.w, a3.w);
    }
    const int cq = bx * 256 + tid;
    ((float4*)(wsp + (size_t)(ch * 4 + 0) * HID))[cq] = a0;
    ((float4*)(wsp + (size_t)(ch * 4 + 1) * HID))[cq] = a1;
    ((float4*)(wsp + (size_t)(ch * 4 + 2) * HID))[cq] = a2;
    ((float4*)(wsp + (size_t)(ch * 4 + 3) * HID))[cq] = a3;
}

// ---------------- Kernel 6: reduce out partials -> d_out ----------------
__global__ __launch_bounds__(256) void k_out_red(const float* __restrict__ wsp,
                                                 float* __restrict__ out) {
    const int c = blockIdx.x * 256 + threadIdx.x;   // 0..4095
    float s[BB] = {0.f, 0.f, 0.f, 0.f};
    #pragma unroll 4
    for (int ch = 0; ch < NCH2; ++ch) {
        #pragma unroll
        for (int b = 0; b < BB; ++b) s[b] += wsp[(size_t)(ch * 4 + b) * HID + c];
    }
    #pragma unroll
    for (int b = 0; b < BB; ++b) out[b * HID + c] = s[b];
}

extern "C" void kernel_launch(void* const* d_in, const int* in_sizes, int n_in,
                              void* d_out, int out_size, void* d_ws, size_t ws_size,
                              hipStream_t stream) {
    const float* hidden = (const float*)d_in[0];
    const float* cosp   = (const float*)d_in[1];
    const float* sinp   = (const float*)d_in[2];
    const float* pk     = (const float*)d_in[3];
    const float* pv     = (const float*)d_in[4];
    const float* wq     = (const float*)d_in[5];
    const float* wk     = (const float*)d_in[6];
    const float* wv     = (const float*)d_in[7];
    const float* wo     = (const float*)d_in[8];
    float* out = (float*)d_out;
    float* ws  = (float*)d_ws;
    float* wsp = ws + OFF_P;

    k_qkv    <<<dim3(6, NCH1), 256, 0, stream>>>(hidden, wq, wk, wv, wsp);
    k_qkv_red<<<24,            256, 0, stream>>>(wsp, cosp, sinp, ws);
    k_scores <<<BB * HKV * 16, 256, 0, stream>>>(pk, ws);
    k_attn   <<<BB * HQ,       256, 0, stream>>>(pv, ws);
    k_out    <<<dim3(4, NCH2), 256, 0, stream>>>(ws, wo, wsp);
    k_out_red<<<16,            256, 0, stream>>>(wsp, out);
}

// Round 3
// 439.933 us; speedup vs baseline: 1.4829x; 1.1937x over previous
//
#include <hip/hip_runtime.h>
#include <cstdint>
#include <cstddef>

#define BB 4
#define HQ 32
#define HKV 8
#define DD 128
#define S_PAST 8192
#define HID 4096
#define KVLEN 8193                 // S_PAST + 1
#define TOKEN_BUDGET 256
#define INIT_BUDGET 4
#define RECENT_BUDGET 256
#define ALLOW_LO INIT_BUDGET       // 4
#define ALLOW_HI (KVLEN - 1 - RECENT_BUDGET)  // 7936 inclusive
#define RECENT_LO (KVLEN - RECENT_BUDGET)     // 7937
#define SSTRIDE 8224

// ws layout in floats. Partials (OFF_P) alias the score region: qkv partials are
// dead before k_scores writes scores; out partials are written after k_attn has
// consumed scores. Max footprint 1613824 floats = 6.5 MB (< proven 8.5 MB).
#define OFF_Q 0                       // [B][HQ*D]   = 16384
#define OFF_K 16384                   // [B][HKV*D]  = 4096
#define OFF_V 20480                   // [B][HKV*D]  = 4096
#define OFF_A 24576                   // [B][HQ*D]   = 16384
#define OFF_S 40960                   // [B][HQ][SSTRIDE] = 1052672
#define OFF_P 40960                   // aliases scores (see above)

#define NCH1 64   // K-chunks for qkv GEMV (64 rows/chunk)
#define NCH2 64   // K-chunks for out GEMV (64 rows/chunk)

__device__ __forceinline__ unsigned fkey(float f) {
    unsigned u = __float_as_uint(f);
    return (u & 0x80000000u) ? ~u : (u | 0x80000000u); // monotone order-preserving map
}

// ---------------- Kernel 1: fused QKV GEMV, 8-deep float4 pipeline ----------------
// grid (6, NCH1) = 384 blocks; bx covers 1024 cols (4/thread); chunk covers 64 rows.
__global__ __launch_bounds__(256) void k_qkv(const float* __restrict__ hidden,
                                             const float* __restrict__ wq,
                                             const float* __restrict__ wk,
                                             const float* __restrict__ wv,
                                             float* __restrict__ wsp) {
    __shared__ float hs[BB][64];
    const int tid = threadIdx.x;
    const int bx = blockIdx.x, ch = blockIdx.y;
    const int i0 = ch * 64;
    if (tid < BB * 64) {
        int b = tid >> 6, ii = tid & 63;
        hs[b][ii] = hidden[b * HID + i0 + ii];
    }
    __syncthreads();
    const int c4 = bx * 1024 + tid * 4;
    const float* w; int stride; int local;
    if (bx < 4)       { w = wq; stride = HQ  * DD; local = c4;        }
    else if (bx == 4) { w = wk; stride = HKV * DD; local = c4 - 4096; }
    else              { w = wv; stride = HKV * DD; local = c4 - 5120; }
    const float* wp = w + (size_t)i0 * stride + local;
    float4 a0 = {0,0,0,0}, a1 = {0,0,0,0}, a2 = {0,0,0,0}, a3 = {0,0,0,0};
    for (int ii = 0; ii < 64; ii += 8) {
        float4 wr[8];
        #pragma unroll
        for (int u = 0; u < 8; ++u)
            wr[u] = *(const float4*)(wp + (size_t)(ii + u) * stride);
        #pragma unroll
        for (int u = 0; u < 8; ++u) {
            float h0 = hs[0][ii+u], h1 = hs[1][ii+u], h2 = hs[2][ii+u], h3 = hs[3][ii+u];
            float4 w4 = wr[u];
            a0.x = fmaf(h0, w4.x, a0.x); a0.y = fmaf(h0, w4.y, a0.y); a0.z = fmaf(h0, w4.z, a0.z); a0.w = fmaf(h0, w4.w, a0.w);
            a1.x = fmaf(h1, w4.x, a1.x); a1.y = fmaf(h1, w4.y, a1.y); a1.z = fmaf(h1, w4.z, a1.z); a1.w = fmaf(h1, w4.w, a1.w);
            a2.x = fmaf(h2, w4.x, a2.x); a2.y = fmaf(h2, w4.y, a2.y); a2.z = fmaf(h2, w4.z, a2.z); a2.w = fmaf(h2, w4.w, a2.w);
            a3.x = fmaf(h3, w4.x, a3.x); a3.y = fmaf(h3, w4.y, a3.y); a3.z = fmaf(h3, w4.z, a3.z); a3.w = fmaf(h3, w4.w, a3.w);
        }
    }
    const int cq = bx * 256 + tid;
    ((float4*)(wsp + (size_t)(ch * 4 + 0) * 6144))[cq] = a0;
    ((float4*)(wsp + (size_t)(ch * 4 + 1) * 6144))[cq] = a1;
    ((float4*)(wsp + (size_t)(ch * 4 + 2) * 6144))[cq] = a2;
    ((float4*)(wsp + (size_t)(ch * 4 + 3) * 6144))[cq] = a3;
}

// ---------------- Kernel 2: reduce qkv partials + fused RoPE ----------------
// grid 48 blocks; block covers 128 cols x 2 chunk-halves (tid>>7).
__global__ __launch_bounds__(256) void k_qkv_red(const float* __restrict__ wsp,
                                                 const float* __restrict__ cosp,
                                                 const float* __restrict__ sinp,
                                                 float* __restrict__ ws) {
    __shared__ float sh[2][BB][128];
    const int tid = threadIdx.x;
    const int i = tid & 127, half = tid >> 7;
    const int c = blockIdx.x * 128 + i;
    float s0 = 0.f, s1 = 0.f, s2 = 0.f, s3 = 0.f;
    for (int cb = 0; cb < 32; cb += 8) {
        float r[8][4];
        #pragma unroll
        for (int u = 0; u < 8; ++u) {
            const float* p = wsp + (size_t)((half * 32 + cb + u) * 4) * 6144 + c;
            r[u][0] = p[0]; r[u][1] = p[6144]; r[u][2] = p[2 * 6144]; r[u][3] = p[3 * 6144];
        }
        #pragma unroll
        for (int u = 0; u < 8; ++u) { s0 += r[u][0]; s1 += r[u][1]; s2 += r[u][2]; s3 += r[u][3]; }
    }
    sh[half][0][i] = s0; sh[half][1][i] = s1; sh[half][2][i] = s2; sh[half][3][i] = s3;
    __syncthreads();
    if (tid < 128) {
        #pragma unroll
        for (int b = 0; b < BB; ++b) {
            float val  = sh[0][b][i] + sh[1][b][i];
            if (c < 5120) {  // rope on q and k_new
                float part = sh[0][b][i ^ 64] + sh[1][b][i ^ 64];
                float rot = (i < 64) ? -part : part;
                val = fmaf(val, cosp[b * DD + i], rot * sinp[b * DD + i]);
            }
            float* dst;
            if (c < 4096)      dst = ws + OFF_Q + b * HQ * DD + c;
            else if (c < 5120) dst = ws + OFF_K + b * HKV * DD + (c - 4096);
            else               dst = ws + OFF_V + b * HKV * DD + (c - 5120);
            *dst = val;
        }
    }
}

// ---------------- Kernel 3: scores; 32 lanes per K-row, 4 rows in flight ----------------
// grid B*HKV*32 = 1024 blocks; 8 groups/block; group g owns rows g+8k of its 256-row chunk.
__global__ __launch_bounds__(256) void k_scores(const float* __restrict__ past_key,
                                                float* __restrict__ ws) {
    const int tid = threadIdx.x, blk = blockIdx.x;
    const int chunk = blk & 31, bkv = blk >> 5;
    const int b = bkv >> 3, kv = bkv & 7;
    const int l = tid & 31, g = tid >> 5;
    const float scale = 0.08838834764831845f; // 1/sqrt(128)
    const float4* qbase = (const float4*)(ws + OFF_Q + ((size_t)b * HQ + kv * 4) * DD);
    float4 q0 = qbase[l], q1 = qbase[32 + l], q2 = qbase[64 + l], q3 = qbase[96 + l];
    q0.x *= scale; q0.y *= scale; q0.z *= scale; q0.w *= scale;
    q1.x *= scale; q1.y *= scale; q1.z *= scale; q1.w *= scale;
    q2.x *= scale; q2.y *= scale; q2.z *= scale; q2.w *= scale;
    q3.x *= scale; q3.y *= scale; q3.z *= scale; q3.w *= scale;
    const float* kbase = past_key + (size_t)(b * HKV + kv) * S_PAST * DD;
    const float4* knew = (const float4*)(ws + OFF_K + (b * HKV + kv) * DD);
    float* srow = ws + OFF_S + (size_t)(b * HQ + kv * 4) * SSTRIDE;
    const int base = chunk * 256;
    for (int rr = g; rr < 256; rr += 32) {
        float4 k4[4];
        #pragma unroll
        for (int t = 0; t < 4; ++t)
            k4[t] = ((const float4*)(kbase + (size_t)(base + rr + 8 * t) * DD))[l];
        float p[4][4];
        #pragma unroll
        for (int t = 0; t < 4; ++t) {
            p[t][0] = k4[t].x*q0.x + k4[t].y*q0.y + k4[t].z*q0.z + k4[t].w*q0.w;
            p[t][1] = k4[t].x*q1.x + k4[t].y*q1.y + k4[t].z*q1.z + k4[t].w*q1.w;
            p[t][2] = k4[t].x*q2.x + k4[t].y*q2.y + k4[t].z*q2.z + k4[t].w*q2.w;
            p[t][3] = k4[t].x*q3.x + k4[t].y*q3.y + k4[t].z*q3.z + k4[t].w*q3.w;
        }
        #pragma unroll
        for (int off = 16; off; off >>= 1) {
            #pragma unroll
            for (int t = 0; t < 4; ++t) {
                p[t][0] += __shfl_xor(p[t][0], off);
                p[t][1] += __shfl_xor(p[t][1], off);
                p[t][2] += __shfl_xor(p[t][2], off);
                p[t][3] += __shfl_xor(p[t][3], off);
            }
        }
        if (l == 0) {
            #pragma unroll
            for (int t = 0; t < 4; ++t) {
                const int j = base + rr + 8 * t;
                srow[0 * SSTRIDE + j] = p[t][0];
                srow[1 * SSTRIDE + j] = p[t][1];
                srow[2 * SSTRIDE + j] = p[t][2];
                srow[3 * SSTRIDE + j] = p[t][3];
            }
        }
    }
    if (chunk == 31 && g == 0) {   // tail row j = 8192 (k_new)
        float4 k4 = knew[l];
        float p0 = k4.x*q0.x + k4.y*q0.y + k4.z*q0.z + k4.w*q0.w;
        float p1 = k4.x*q1.x + k4.y*q1.y + k4.z*q1.z + k4.w*q1.w;
        float p2 = k4.x*q2.x + k4.y*q2.y + k4.z*q2.z + k4.w*q2.w;
        float p3 = k4.x*q3.x + k4.y*q3.y + k4.z*q3.z + k4.w*q3.w;
        #pragma unroll
        for (int off = 16; off; off >>= 1) {
            p0 += __shfl_xor(p0, off); p1 += __shfl_xor(p1, off);
            p2 += __shfl_xor(p2, off); p3 += __shfl_xor(p3, off);
        }
        if (l == 0) {
            srow[0 * SSTRIDE + 8192] = p0; srow[1 * SSTRIDE + 8192] = p1;
            srow[2 * SSTRIDE + 8192] = p2; srow[3 * SSTRIDE + 8192] = p3;
        }
    }
}

// Wave-level suffix-select over 256 bucket counts (in sbuf). Lane t<64 holds 4 buckets.
// Finds bucket with suffix >= K > next-suffix; outputs bucket id, count above it, own count.
__device__ __forceinline__ void suffix_select(const int* sbuf, int K,
                                              int* s_bucket, int* s_above, int* s_cntb,
                                              int tid) {
    if (tid < 64) {
        int4 h = ((const int4*)sbuf)[tid];
        int c = h.x + h.y + h.z + h.w;
        int x = c;
        #pragma unroll
        for (int off = 1; off < 64; off <<= 1) {
            int y = __shfl_down(x, off);
            if (tid + off < 64) x += y;
        }
        int excl = x - c;             // suffix starting at next chunk
        int s3 = excl + h.w;
        int s2 = s3 + h.z;
        int s1 = s2 + h.y;
        int s0 = s1 + h.x;
        if (s0 >= K && s1  < K) { *s_bucket = 4*tid+0; *s_above = s1;   *s_cntb = h.x; }
        if (s1 >= K && s2  < K) { *s_bucket = 4*tid+1; *s_above = s2;   *s_cntb = h.y; }
        if (s2 >= K && s3  < K) { *s_bucket = 4*tid+2; *s_above = s3;   *s_cntb = h.z; }
        if (s3 >= K && excl < K){ *s_bucket = 4*tid+3; *s_above = excl; *s_cntb = h.w; }
    }
}

// ---------------- Kernel 4: per-(b,h) exact top-k + softmax + A@V ----------------
__global__ __launch_bounds__(256) void k_attn(const float* __restrict__ past_value,
                                              float* __restrict__ ws) {
    const int tid = threadIdx.x;
    const int blk = blockIdx.x;          // B*HQ = 128
    const int b = blk >> 5, h = blk & 31, kv = h >> 2;
    const float* srow = ws + OFF_S + (size_t)(b * HQ + h) * SSTRIDE;

    __shared__ int   hist4[4][256];
    __shared__ int   sbuf[256];
    __shared__ float redm[4];
    __shared__ int   cand[7936];
    __shared__ int   s_bucket, s_above, s_cntb, s_ccnt, s_cnt;
    __shared__ int   s_lo, s_hi, s_tc;
    __shared__ float s_sum;
    __shared__ int   list[520];
    __shared__ float wl[520];
    __shared__ float red[8][DD];

    int* hflat = &hist4[0][0];
    const int wv_ = tid >> 6;

    // ---- pass A: fused row-max + top-byte histogram ----
    for (int i = tid; i < 1024; i += 256) hflat[i] = 0;
    if (tid == 0) { s_ccnt = 0; s_cnt = 0; s_sum = 0.f; }
    __syncthreads();
    float m = -3.4e38f;
    for (int j = tid; j < KVLEN; j += 256) {
        float s = srow[j];
        m = fmaxf(m, s);
        if (j >= ALLOW_LO && j <= ALLOW_HI)
            atomicAdd(&hist4[wv_][fkey(s) >> 24], 1);
    }
    #pragma unroll
    for (int off = 32; off; off >>= 1) m = fmaxf(m, __shfl_xor(m, off));
    if ((tid & 63) == 0) redm[tid >> 6] = m;
    __syncthreads();
    m = fmaxf(fmaxf(redm[0], redm[1]), fmaxf(redm[2], redm[3]));
    sbuf[tid] = hist4[0][tid] + hist4[1][tid] + hist4[2][tid] + hist4[3][tid];
    __syncthreads();
    int K = TOKEN_BUDGET;
    suffix_select(sbuf, K, &s_bucket, &s_above, &s_cntb, tid);
    __syncthreads();
    K -= s_above;
    unsigned prefix = (unsigned)s_bucket;   // top byte
    __syncthreads();

    // ---- pass B: second byte histogram + candidate compaction ----
    for (int i = tid; i < 1024; i += 256) hflat[i] = 0;
    __syncthreads();
    for (int j = ALLOW_LO + tid; j <= ALLOW_HI; j += 256) {
        unsigned u = fkey(srow[j]);
        if ((u >> 24) == prefix) {
            int p = atomicAdd(&s_ccnt, 1);
            cand[p] = j;
            atomicAdd(&hist4[wv_][(u >> 16) & 255], 1);
        }
    }
    __syncthreads();
    const int ccnt = s_ccnt;
    sbuf[tid] = hist4[0][tid] + hist4[1][tid] + hist4[2][tid] + hist4[3][tid];
    __syncthreads();
    suffix_select(sbuf, K, &s_bucket, &s_above, &s_cntb, tid);
    __syncthreads();
    K -= s_above;
    prefix = (prefix << 8) | (unsigned)s_bucket;
    __syncthreads();

    // ---- pass C: third byte over candidates ----
    for (int i = tid; i < 1024; i += 256) hflat[i] = 0;
    __syncthreads();
    for (int i = tid; i < ccnt; i += 256) {
        unsigned u = fkey(srow[cand[i]]);
        if ((u >> 16) == prefix) atomicAdd(&hist4[wv_][(u >> 8) & 255], 1);
    }
    __syncthreads();
    sbuf[tid] = hist4[0][tid] + hist4[1][tid] + hist4[2][tid] + hist4[3][tid];
    __syncthreads();
    suffix_select(sbuf, K, &s_bucket, &s_above, &s_cntb, tid);
    __syncthreads();
    K -= s_above;
    prefix = (prefix << 8) | (unsigned)s_bucket;
    __syncthreads();

    // ---- pass D: last byte over candidates ----
    for (int i = tid; i < 1024; i += 256) hflat[i] = 0;
    __syncthreads();
    for (int i = tid; i < ccnt; i += 256) {
        unsigned u = fkey(srow[cand[i]]);
        if ((u >> 8) == prefix) atomicAdd(&hist4[wv_][u & 255], 1);
    }
    __syncthreads();
    sbuf[tid] = hist4[0][tid] + hist4[1][tid] + hist4[2][tid] + hist4[3][tid];
    __syncthreads();
    suffix_select(sbuf, K, &s_bucket, &s_above, &s_cntb, tid);
    __syncthreads();
    const int T = K - s_above;               // equals to keep (lowest j first)
    const int E = s_cntb;                    // equals available
    const unsigned tkey = (prefix << 8) | (unsigned)s_bucket;
    __syncthreads();

    // ---- tie boundary (rare): smallest jcut with count(key==tkey, j<=jcut) >= T ----
    int jcut = ALLOW_HI;
    if (E > T) {
        if (tid == 0) { s_lo = ALLOW_LO; s_hi = ALLOW_HI; }
        __syncthreads();
        while (true) {
            int lo = s_lo, hi = s_hi;
            if (lo >= hi) break;
            int mid = (lo + hi) >> 1;
            if (tid == 0) s_tc = 0;
            __syncthreads();
            int local = 0;
            for (int i = tid; i < ccnt; i += 256) {
                int j = cand[i];
                if (j <= mid && fkey(srow[j]) == tkey) local++;
            }
            atomicAdd(&s_tc, local);
            __syncthreads();
            if (tid == 0) { if (s_tc >= T) s_hi = mid; else s_lo = mid + 1; }
            __syncthreads();
        }
        jcut = s_lo;
    }
    __syncthreads();

    // ---- compact kept set + softmax weights ----
    for (int j = tid; j < KVLEN; j += 256) {
        float s = srow[j];
        bool keep;
        if (j < INIT_BUDGET || j >= RECENT_LO) keep = true;
        else {
            unsigned u = fkey(s);
            keep = (u > tkey) || (u == tkey && j <= jcut);
        }
        if (keep) {
            float e = __expf(s - m);
            int p = atomicAdd(&s_cnt, 1);
            list[p] = j; wl[p] = e;
            atomicAdd(&s_sum, e);
        }
    }
    __syncthreads();
    const int cnt = s_cnt;           // = 516
    const float inv = 1.0f / s_sum;

    // ---- gathered A@V: 8 groups x 32 lanes, 4 rows in flight ----
    const int g = tid >> 5, dq = tid & 31;
    const float4* vnew = (const float4*)(ws + OFF_V + (b * HKV + kv) * DD);
    const float* vbase = past_value + (size_t)(b * HKV + kv) * S_PAST * DD;
    float4 acc = {0.f, 0.f, 0.f, 0.f};
    for (int e = g; e < cnt; e += 32) {
        int jj[4]; float wv4[4]; float4 v4[4];
        #pragma unroll
        for (int k = 0; k < 4; ++k) {
            int ee = e + 8 * k;
            bool ok = ee < cnt;
            jj[k]  = ok ? list[ee] : 0;
            wv4[k] = ok ? wl[ee]   : 0.f;
        }
        #pragma unroll
        for (int k = 0; k < 4; ++k) {
            int j = jj[k];
            v4[k] = (j < S_PAST) ? ((const float4*)(vbase + (size_t)j * DD))[dq] : vnew[dq];
        }
        #pragma unroll
        for (int k = 0; k < 4; ++k) {
            acc.x = fmaf(wv4[k], v4[k].x, acc.x);
            acc.y = fmaf(wv4[k], v4[k].y, acc.y);
            acc.z = fmaf(wv4[k], v4[k].z, acc.z);
            acc.w = fmaf(wv4[k], v4[k].w, acc.w);
        }
    }
    red[g][dq * 4 + 0] = acc.x; red[g][dq * 4 + 1] = acc.y;
    red[g][dq * 4 + 2] = acc.z; red[g][dq * 4 + 3] = acc.w;
    __syncthreads();
    if (tid < DD) {
        float s = 0.f;
        #pragma unroll
        for (int gg = 0; gg < 8; ++gg) s += red[gg][tid];
        ws[OFF_A + b * HQ * DD + h * DD + tid] = s * inv;
    }
}

// ---------------- Kernel 5: output GEMV, 8-deep float4 pipeline ----------------
// grid (4, NCH2) = 256 blocks; bx covers 1024 cols; chunk covers 64 rows.
__global__ __launch_bounds__(256) void k_out(const float* __restrict__ ws,
                                             const float* __restrict__ wo,
                                             float* __restrict__ wsp) {
    __shared__ float a[BB][64];
    const int tid = threadIdx.x;
    const int bx = blockIdx.x, ch = blockIdx.y;
    const int i0 = ch * 64;
    if (tid < BB * 64) {
        int b = tid >> 6, ii = tid & 63;
        a[b][ii] = ws[OFF_A + b * HQ * DD + i0 + ii];
    }
    __syncthreads();
    const int c4 = bx * 1024 + tid * 4;
    const float* wp = wo + (size_t)i0 * HID + c4;
    float4 a0 = {0,0,0,0}, a1 = {0,0,0,0}, a2 = {0,0,0,0}, a3 = {0,0,0,0};
    for (int ii = 0; ii < 64; ii += 8) {
        float4 wr[8];
        #pragma unroll
        for (int u = 0; u < 8; ++u)
            wr[u] = *(const float4*)(wp + (size_t)(ii + u) * HID);
        #pragma unroll
        for (int u = 0; u < 8; ++u) {
            float h0 = a[0][ii+u], h1 = a[1][ii+u], h2 = a[2][ii+u], h3 = a[3][ii+u];
            float4 w4 = wr[u];
            a0.x = fmaf(h0, w4.x, a0.x); a0.y = fmaf(h0, w4.y, a0.y); a0.z = fmaf(h0, w4.z, a0.z); a0.w = fmaf(h0, w4.w, a0.w);
            a1.x = fmaf(h1, w4.x, a1.x); a1.y = fmaf(h1, w4.y, a1.y); a1.z = fmaf(h1, w4.z, a1.z); a1.w = fmaf(h1, w4.w, a1.w);
            a2.x = fmaf(h2, w4.x, a2.x); a2.y = fmaf(h2, w4.y, a2.y); a2.z = fmaf(h2, w4.z, a2.z); a2.w = fmaf(h2, w4.w, a2.w);
            a3.x = fmaf(h3, w4.x, a3.x); a3.y = fmaf(h3, w4.y, a3.y); a3.z = fmaf(h3, w4.z, a3.z); a3.w = fmaf(h3, w4.w, a3.w);
        }
    }
    const int cq = bx * 256 + tid;
    ((float4*)(wsp + (size_t)(ch * 4 + 0) * HID))[cq] = a0;
    ((float4*)(wsp + (size_t)(ch * 4 + 1) * HID))[cq] = a1;
    ((float4*)(wsp + (size_t)(ch * 4 + 2) * HID))[cq] = a2;
    ((float4*)(wsp + (size_t)(ch * 4 + 3) * HID))[cq] = a3;
}

// ---------------- Kernel 6: reduce out partials -> d_out ----------------
// grid 32 blocks; block covers 128 cols x 2 chunk-halves.
__global__ __launch_bounds__(256) void k_out_red(const float* __restrict__ wsp,
                                                 float* __restrict__ out) {
    __shared__ float sh[2][BB][128];
    const int tid = threadIdx.x;
    const int i = tid & 127, half = tid >> 7;
    const int c = blockIdx.x * 128 + i;
    float s0 = 0.f, s1 = 0.f, s2 = 0.f, s3 = 0.f;
    for (int cb = 0; cb < 32; cb += 8) {
        float r[8][4];
        #pragma unroll
        for (int u = 0; u < 8; ++u) {
            const float* p = wsp + (size_t)((half * 32 + cb + u) * 4) * HID + c;
            r[u][0] = p[0]; r[u][1] = p[HID]; r[u][2] = p[2 * HID]; r[u][3] = p[3 * HID];
        }
        #pragma unroll
        for (int u = 0; u < 8; ++u) { s0 += r[u][0]; s1 += r[u][1]; s2 += r[u][2]; s3 += r[u][3]; }
    }
    sh[half][0][i] = s0; sh[half][1][i] = s1; sh[half][2][i] = s2; sh[half][3][i] = s3;
    __syncthreads();
    if (tid < 128) {
        #pragma unroll
        for (int b = 0; b < BB; ++b)
            out[b * HID + c] = sh[0][b][i] + sh[1][b][i];
    }
}

extern "C" void kernel_launch(void* const* d_in, const int* in_sizes, int n_in,
                              void* d_out, int out_size, void* d_ws, size_t ws_size,
                              hipStream_t stream) {
    const float* hidden = (const float*)d_in[0];
    const float* cosp   = (const float*)d_in[1];
    const float* sinp   = (const float*)d_in[2];
    const float* pk     = (const float*)d_in[3];
    const float* pv     = (const float*)d_in[4];
    const float* wq     = (const float*)d_in[5];
    const float* wk     = (const float*)d_in[6];
    const float* wv     = (const float*)d_in[7];
    const float* wo     = (const float*)d_in[8];
    float* out = (float*)d_out;
    float* ws  = (float*)d_ws;
    float* wsp = ws + OFF_P;

    k_qkv    <<<dim3(6, NCH1), 256, 0, stream>>>(hidden, wq, wk, wv, wsp);
    k_qkv_red<<<48,            256, 0, stream>>>(wsp, cosp, sinp, ws);
    k_scores <<<BB * HKV * 32, 256, 0, stream>>>(pk, ws);
    k_attn   <<<BB * HQ,       256, 0, stream>>>(pv, ws);
    k_out    <<<dim3(4, NCH2), 256, 0, stream>>>(ws, wo, wsp);
    k_out_red<<<32,            256, 0, stream>>>(wsp, out);
}

// Round 4
// 421.700 us; speedup vs baseline: 1.5470x; 1.0432x over previous
//
#include <hip/hip_runtime.h>
#include <cstdint>
#include <cstddef>

#define BB 4
#define HQ 32
#define HKV 8
#define DD 128
#define S_PAST 8192
#define HID 4096
#define KVLEN 8193                 // S_PAST + 1
#define TOKEN_BUDGET 256
#define INIT_BUDGET 4
#define RECENT_BUDGET 256
#define ALLOW_LO INIT_BUDGET       // 4
#define ALLOW_HI (KVLEN - 1 - RECENT_BUDGET)  // 7936 inclusive
#define RECENT_LO (KVLEN - RECENT_BUDGET)     // 7937
#define SSTRIDE 8224

// ws layout in floats. Partials (OFF_P) alias the score region: qkv partials are
// dead before k_scores writes scores; out partials are written after k_attn has
// consumed scores.
#define OFF_Q 0                       // [B][HQ*D]   = 16384
#define OFF_K 16384                   // [B][HKV*D]  = 4096
#define OFF_V 20480                   // [B][HKV*D]  = 4096
#define OFF_A 24576                   // [B][HQ*D]   = 16384
#define OFF_S 40960                   // [B][HQ][SSTRIDE] = 1052672
#define OFF_P 40960                   // aliases scores (see above)

#define NCH1 64   // K-chunks for qkv GEMV (64 rows/chunk)
#define NCH2 64   // K-chunks for out GEMV (64 rows/chunk)

__device__ __forceinline__ unsigned fkey(float f) {
    unsigned u = __float_as_uint(f);
    return (u & 0x80000000u) ? ~u : (u | 0x80000000u); // monotone order-preserving map
}

// ---------------- Kernel 1: fused QKV GEMV, 8-deep float4 pipeline ----------------
__global__ __launch_bounds__(256) void k_qkv(const float* __restrict__ hidden,
                                             const float* __restrict__ wq,
                                             const float* __restrict__ wk,
                                             const float* __restrict__ wv,
                                             float* __restrict__ wsp) {
    __shared__ float hs[BB][64];
    const int tid = threadIdx.x;
    const int bx = blockIdx.x, ch = blockIdx.y;
    const int i0 = ch * 64;
    if (tid < BB * 64) {
        int b = tid >> 6, ii = tid & 63;
        hs[b][ii] = hidden[b * HID + i0 + ii];
    }
    __syncthreads();
    const int c4 = bx * 1024 + tid * 4;
    const float* w; int stride; int local;
    if (bx < 4)       { w = wq; stride = HQ  * DD; local = c4;        }
    else if (bx == 4) { w = wk; stride = HKV * DD; local = c4 - 4096; }
    else              { w = wv; stride = HKV * DD; local = c4 - 5120; }
    const float* wp = w + (size_t)i0 * stride + local;
    float4 a0 = {0,0,0,0}, a1 = {0,0,0,0}, a2 = {0,0,0,0}, a3 = {0,0,0,0};
    for (int ii = 0; ii < 64; ii += 8) {
        float4 wr[8];
        #pragma unroll
        for (int u = 0; u < 8; ++u)
            wr[u] = *(const float4*)(wp + (size_t)(ii + u) * stride);
        #pragma unroll
        for (int u = 0; u < 8; ++u) {
            float h0 = hs[0][ii+u], h1 = hs[1][ii+u], h2 = hs[2][ii+u], h3 = hs[3][ii+u];
            float4 w4 = wr[u];
            a0.x = fmaf(h0, w4.x, a0.x); a0.y = fmaf(h0, w4.y, a0.y); a0.z = fmaf(h0, w4.z, a0.z); a0.w = fmaf(h0, w4.w, a0.w);
            a1.x = fmaf(h1, w4.x, a1.x); a1.y = fmaf(h1, w4.y, a1.y); a1.z = fmaf(h1, w4.z, a1.z); a1.w = fmaf(h1, w4.w, a1.w);
            a2.x = fmaf(h2, w4.x, a2.x); a2.y = fmaf(h2, w4.y, a2.y); a2.z = fmaf(h2, w4.z, a2.z); a2.w = fmaf(h2, w4.w, a2.w);
            a3.x = fmaf(h3, w4.x, a3.x); a3.y = fmaf(h3, w4.y, a3.y); a3.z = fmaf(h3, w4.z, a3.z); a3.w = fmaf(h3, w4.w, a3.w);
        }
    }
    const int cq = bx * 256 + tid;
    ((float4*)(wsp + (size_t)(ch * 4 + 0) * 6144))[cq] = a0;
    ((float4*)(wsp + (size_t)(ch * 4 + 1) * 6144))[cq] = a1;
    ((float4*)(wsp + (size_t)(ch * 4 + 2) * 6144))[cq] = a2;
    ((float4*)(wsp + (size_t)(ch * 4 + 3) * 6144))[cq] = a3;
}

// ---------------- Kernel 2: reduce qkv partials + fused RoPE ----------------
__global__ __launch_bounds__(256) void k_qkv_red(const float* __restrict__ wsp,
                                                 const float* __restrict__ cosp,
                                                 const float* __restrict__ sinp,
                                                 float* __restrict__ ws) {
    __shared__ float sh[2][BB][128];
    const int tid = threadIdx.x;
    const int i = tid & 127, half = tid >> 7;
    const int c = blockIdx.x * 128 + i;
    float s0 = 0.f, s1 = 0.f, s2 = 0.f, s3 = 0.f;
    for (int cb = 0; cb < 32; cb += 8) {
        float r[8][4];
        #pragma unroll
        for (int u = 0; u < 8; ++u) {
            const float* p = wsp + (size_t)((half * 32 + cb + u) * 4) * 6144 + c;
            r[u][0] = p[0]; r[u][1] = p[6144]; r[u][2] = p[2 * 6144]; r[u][3] = p[3 * 6144];
        }
        #pragma unroll
        for (int u = 0; u < 8; ++u) { s0 += r[u][0]; s1 += r[u][1]; s2 += r[u][2]; s3 += r[u][3]; }
    }
    sh[half][0][i] = s0; sh[half][1][i] = s1; sh[half][2][i] = s2; sh[half][3][i] = s3;
    __syncthreads();
    if (tid < 128) {
        #pragma unroll
        for (int b = 0; b < BB; ++b) {
            float val  = sh[0][b][i] + sh[1][b][i];
            if (c < 5120) {  // rope on q and k_new
                float part = sh[0][b][i ^ 64] + sh[1][b][i ^ 64];
                float rot = (i < 64) ? -part : part;
                val = fmaf(val, cosp[b * DD + i], rot * sinp[b * DD + i]);
            }
            float* dst;
            if (c < 4096)      dst = ws + OFF_Q + b * HQ * DD + c;
            else if (c < 5120) dst = ws + OFF_K + b * HKV * DD + (c - 4096);
            else               dst = ws + OFF_V + b * HKV * DD + (c - 5120);
            *dst = val;
        }
    }
}

// ---------------- Kernel 3: scores; 32 lanes per K-row, 4 rows in flight ----------------
__global__ __launch_bounds__(256) void k_scores(const float* __restrict__ past_key,
                                                float* __restrict__ ws) {
    const int tid = threadIdx.x, blk = blockIdx.x;
    const int chunk = blk & 31, bkv = blk >> 5;
    const int b = bkv >> 3, kv = bkv & 7;
    const int l = tid & 31, g = tid >> 5;
    const float scale = 0.08838834764831845f; // 1/sqrt(128)
    const float4* qbase = (const float4*)(ws + OFF_Q + ((size_t)b * HQ + kv * 4) * DD);
    float4 q0 = qbase[l], q1 = qbase[32 + l], q2 = qbase[64 + l], q3 = qbase[96 + l];
    q0.x *= scale; q0.y *= scale; q0.z *= scale; q0.w *= scale;
    q1.x *= scale; q1.y *= scale; q1.z *= scale; q1.w *= scale;
    q2.x *= scale; q2.y *= scale; q2.z *= scale; q2.w *= scale;
    q3.x *= scale; q3.y *= scale; q3.z *= scale; q3.w *= scale;
    const float* kbase = past_key + (size_t)(b * HKV + kv) * S_PAST * DD;
    const float4* knew = (const float4*)(ws + OFF_K + (b * HKV + kv) * DD);
    float* srow = ws + OFF_S + (size_t)(b * HQ + kv * 4) * SSTRIDE;
    const int base = chunk * 256;
    for (int rr = g; rr < 256; rr += 32) {
        float4 k4[4];
        #pragma unroll
        for (int t = 0; t < 4; ++t)
            k4[t] = ((const float4*)(kbase + (size_t)(base + rr + 8 * t) * DD))[l];
        float p[4][4];
        #pragma unroll
        for (int t = 0; t < 4; ++t) {
            p[t][0] = k4[t].x*q0.x + k4[t].y*q0.y + k4[t].z*q0.z + k4[t].w*q0.w;
            p[t][1] = k4[t].x*q1.x + k4[t].y*q1.y + k4[t].z*q1.z + k4[t].w*q1.w;
            p[t][2] = k4[t].x*q2.x + k4[t].y*q2.y + k4[t].z*q2.z + k4[t].w*q2.w;
            p[t][3] = k4[t].x*q3.x + k4[t].y*q3.y + k4[t].z*q3.z + k4[t].w*q3.w;
        }
        #pragma unroll
        for (int off = 16; off; off >>= 1) {
            #pragma unroll
            for (int t = 0; t < 4; ++t) {
                p[t][0] += __shfl_xor(p[t][0], off);
                p[t][1] += __shfl_xor(p[t][1], off);
                p[t][2] += __shfl_xor(p[t][2], off);
                p[t][3] += __shfl_xor(p[t][3], off);
            }
        }
        if (l == 0) {
            #pragma unroll
            for (int t = 0; t < 4; ++t) {
                const int j = base + rr + 8 * t;
                srow[0 * SSTRIDE + j] = p[t][0];
                srow[1 * SSTRIDE + j] = p[t][1];
                srow[2 * SSTRIDE + j] = p[t][2];
                srow[3 * SSTRIDE + j] = p[t][3];
            }
        }
    }
    if (chunk == 31 && g == 0) {   // tail row j = 8192 (k_new)
        float4 k4 = knew[l];
        float p0 = k4.x*q0.x + k4.y*q0.y + k4.z*q0.z + k4.w*q0.w;
        float p1 = k4.x*q1.x + k4.y*q1.y + k4.z*q1.z + k4.w*q1.w;
        float p2 = k4.x*q2.x + k4.y*q2.y + k4.z*q2.z + k4.w*q2.w;
        float p3 = k4.x*q3.x + k4.y*q3.y + k4.z*q3.z + k4.w*q3.w;
        #pragma unroll
        for (int off = 16; off; off >>= 1) {
            p0 += __shfl_xor(p0, off); p1 += __shfl_xor(p1, off);
            p2 += __shfl_xor(p2, off); p3 += __shfl_xor(p3, off);
        }
        if (l == 0) {
            srow[0 * SSTRIDE + 8192] = p0; srow[1 * SSTRIDE + 8192] = p1;
            srow[2 * SSTRIDE + 8192] = p2; srow[3 * SSTRIDE + 8192] = p3;
        }
    }
}

// Wave-level suffix-select over 256 bucket counts. Lane t<64 holds 4 buckets.
__device__ __forceinline__ void suffix_select(const int* sbuf, int K,
                                              int* s_bucket, int* s_above, int* s_cntb,
                                              int tid) {
    if (tid < 64) {
        int4 h = ((const int4*)sbuf)[tid];
        int c = h.x + h.y + h.z + h.w;
        int x = c;
        #pragma unroll
        for (int off = 1; off < 64; off <<= 1) {
            int y = __shfl_down(x, off);
            if (tid + off < 64) x += y;
        }
        int excl = x - c;
        int s3 = excl + h.w;
        int s2 = s3 + h.z;
        int s1 = s2 + h.y;
        int s0 = s1 + h.x;
        if (s0 >= K && s1  < K) { *s_bucket = 4*tid+0; *s_above = s1;   *s_cntb = h.x; }
        if (s1 >= K && s2  < K) { *s_bucket = 4*tid+1; *s_above = s2;   *s_cntb = h.y; }
        if (s2 >= K && s3  < K) { *s_bucket = 4*tid+2; *s_above = s3;   *s_cntb = h.z; }
        if (s3 >= K && excl < K){ *s_bucket = 4*tid+3; *s_above = excl; *s_cntb = h.w; }
    }
}

// ---------------- Kernel 4: per-(b,h) top-k + softmax + A@V, LDS-resident row ----------------
__global__ __launch_bounds__(256) void k_attn(const float* __restrict__ past_value,
                                              float* __restrict__ ws) {
    const int tid = threadIdx.x;
    const int blk = blockIdx.x;          // B*HQ = 128
    const int b = blk >> 5, h = blk & 31, kv = h >> 2;
    const float* srow = ws + OFF_S + (size_t)(b * HQ + h) * SSTRIDE;

    __shared__ __align__(16) float rowl[8196];
    __shared__ __align__(16) int   hist[4096];
    __shared__ __align__(16) int   hist2[256];
    __shared__ int   wtot[4];
    __shared__ float redm[4];
    __shared__ int   s_bucket, s_above, s_cntb, s_cnt, s_done;
    __shared__ int   s_lo, s_hi, s_tc;
    __shared__ float s_sum;
    __shared__ int   list[520];
    __shared__ float wl[520];
    __shared__ float red[8][DD];

    for (int i = tid; i < 4096; i += 256) hist[i] = 0;
    if (tid == 0) { s_cnt = 0; s_sum = 0.f; }
    __syncthreads();

    // ---- single pass: row -> LDS (float4) + max + 4096-bin histogram (top 12 bits) ----
    float m = -3.4e38f;
    for (int i4 = tid; i4 < 2048; i4 += 256) {
        float4 v = ((const float4*)srow)[i4];
        ((float4*)rowl)[i4] = v;
        m = fmaxf(fmaxf(m, fmaxf(v.x, v.y)), fmaxf(v.z, v.w));
        if (i4 >= 1 && i4 <= 1983) {          // j = 4*i4.. fully inside [4,7936]
            atomicAdd(&hist[fkey(v.x) >> 20], 1);
            atomicAdd(&hist[fkey(v.y) >> 20], 1);
            atomicAdd(&hist[fkey(v.z) >> 20], 1);
            atomicAdd(&hist[fkey(v.w) >> 20], 1);
        } else {
            int j = i4 * 4;
            if (j+0 >= ALLOW_LO && j+0 <= ALLOW_HI) atomicAdd(&hist[fkey(v.x) >> 20], 1);
            if (j+1 >= ALLOW_LO && j+1 <= ALLOW_HI) atomicAdd(&hist[fkey(v.y) >> 20], 1);
            if (j+2 >= ALLOW_LO && j+2 <= ALLOW_HI) atomicAdd(&hist[fkey(v.z) >> 20], 1);
            if (j+3 >= ALLOW_LO && j+3 <= ALLOW_HI) atomicAdd(&hist[fkey(v.w) >> 20], 1);
        }
    }
    if (tid == 0) { float s = srow[8192]; rowl[8192] = s; m = fmaxf(m, s); }
    #pragma unroll
    for (int off = 32; off; off >>= 1) m = fmaxf(m, __shfl_xor(m, off));
    if ((tid & 63) == 0) redm[tid >> 6] = m;
    __syncthreads();
    m = fmaxf(fmaxf(redm[0], redm[1]), fmaxf(redm[2], redm[3]));

    // ---- hierarchical suffix-select over 4096 bins: thread owns 16 bins ----
    int hc[16]; int csum = 0;
    #pragma unroll
    for (int q = 0; q < 4; ++q) {
        int4 v = ((const int4*)hist)[tid * 4 + q];
        hc[4*q] = v.x; hc[4*q+1] = v.y; hc[4*q+2] = v.z; hc[4*q+3] = v.w;
        csum += v.x + v.y + v.z + v.w;
    }
    {
        const int lane = tid & 63, w = tid >> 6;
        int x = csum;
        #pragma unroll
        for (int off = 1; off < 64; off <<= 1) {
            int y = __shfl_down(x, off);
            if (lane + off < 64) x += y;
        }
        if (lane == 0) wtot[w] = x;
        __syncthreads();
        int high = 0;
        for (int w2 = w + 1; w2 < 4; ++w2) high += wtot[w2];
        int run = (x - csum) + high;       // count in chunks strictly above this thread's
        #pragma unroll
        for (int i = 15; i >= 0; --i) {
            int inc = run + hc[i];
            if (inc >= TOKEN_BUDGET && run < TOKEN_BUDGET) {
                s_bucket = 16 * tid + i; s_above = run; s_cntb = hc[i];
            }
            run = inc;
        }
    }
    __syncthreads();

    int Kc = TOKEN_BUDGET - s_above;
    int E  = s_cntb;
    unsigned pref = (unsigned)s_bucket;    // 12 bits
    unsigned tkey = pref << 20;
    int jcut = ALLOW_HI;
    if (tid == 0) s_done = (E == Kc);
    __syncthreads();

    // ---- refine level 2: bits [19:12] ----
    if (!s_done) {
        hist2[tid] = 0;
        __syncthreads();
        for (int j = ALLOW_LO + tid; j <= ALLOW_HI; j += 256) {
            unsigned u = fkey(rowl[j]);
            if ((u >> 20) == pref) atomicAdd(&hist2[(u >> 12) & 255], 1);
        }
        __syncthreads();
        suffix_select(hist2, Kc, &s_bucket, &s_above, &s_cntb, tid);
        __syncthreads();
        Kc -= s_above; E = s_cntb;
        pref = (pref << 8) | (unsigned)s_bucket;   // 20 bits
        tkey = pref << 12;
        if (tid == 0) s_done = (E == Kc);
        __syncthreads();
    }
    // ---- refine level 3: bits [11:4] ----
    if (!s_done) {
        hist2[tid] = 0;
        __syncthreads();
        for (int j = ALLOW_LO + tid; j <= ALLOW_HI; j += 256) {
            unsigned u = fkey(rowl[j]);
            if ((u >> 12) == pref) atomicAdd(&hist2[(u >> 4) & 255], 1);
        }
        __syncthreads();
        suffix_select(hist2, Kc, &s_bucket, &s_above, &s_cntb, tid);
        __syncthreads();
        Kc -= s_above; E = s_cntb;
        pref = (pref << 8) | (unsigned)s_bucket;   // 28 bits
        tkey = pref << 4;
        if (tid == 0) s_done = (E == Kc);
        __syncthreads();
    }
    // ---- refine level 4: bits [3:0] (exact key) ----
    if (!s_done) {
        hist2[tid] = 0;
        __syncthreads();
        for (int j = ALLOW_LO + tid; j <= ALLOW_HI; j += 256) {
            unsigned u = fkey(rowl[j]);
            if ((u >> 4) == pref) atomicAdd(&hist2[u & 15], 1);
        }
        __syncthreads();
        suffix_select(hist2, Kc, &s_bucket, &s_above, &s_cntb, tid);
        __syncthreads();
        Kc -= s_above; E = s_cntb;
        tkey = (pref << 4) | (unsigned)s_bucket;   // exact 32-bit key of K-th largest
        if (E > Kc) {   // exact ties: find smallest jcut with count(key==tkey, j<=jcut) >= Kc
            if (tid == 0) { s_lo = ALLOW_LO; s_hi = ALLOW_HI; }
            __syncthreads();
            while (s_lo < s_hi) {
                int mid = (s_lo + s_hi) >> 1;
                if (tid == 0) s_tc = 0;
                __syncthreads();
                int loc = 0;
                for (int j = ALLOW_LO + tid; j <= mid; j += 256)
                    if (fkey(rowl[j]) == tkey) loc++;
                if (loc) atomicAdd(&s_tc, loc);
                __syncthreads();
                if (tid == 0) { if (s_tc >= Kc) s_hi = mid; else s_lo = mid + 1; }
                __syncthreads();
            }
            jcut = s_lo;
        }
        __syncthreads();
    }

    // ---- compact kept set (ballot) + softmax weights ----
    float lsum = 0.f;
    const int lane = tid & 63;
    for (int j = tid; j < KVLEN; j += 256) {
        float s = rowl[j];
        bool keep;
        if (j < INIT_BUDGET || j >= RECENT_LO) keep = true;
        else {
            unsigned u = fkey(s);
            keep = (u > tkey) || (u == tkey && j <= jcut);
        }
        unsigned long long mask = __ballot(keep);
        if (mask) {
            int leader = (int)__ffsll((unsigned long long)mask) - 1;
            int cw = __popcll(mask);
            int base = 0;
            if (lane == leader) base = atomicAdd(&s_cnt, cw);
            base = __shfl(base, leader);
            if (keep) {
                int p = base + __popcll(mask & ((1ull << lane) - 1ull));
                float e = __expf(s - m);
                list[p] = j; wl[p] = e;
                lsum += e;
            }
        }
    }
    #pragma unroll
    for (int off = 32; off; off >>= 1) lsum += __shfl_xor(lsum, off);
    if (lane == 0) atomicAdd(&s_sum, lsum);
    __syncthreads();
    const int cnt = s_cnt;           // = 516
    const float inv = 1.0f / s_sum;

    // ---- gathered A@V: 8 groups x 32 lanes, 8 rows in flight ----
    const int g = tid >> 5, dq = tid & 31;
    const float4* vnew = (const float4*)(ws + OFF_V + (b * HKV + kv) * DD);
    const float* vbase = past_value + (size_t)(b * HKV + kv) * S_PAST * DD;
    float4 acc = {0.f, 0.f, 0.f, 0.f};
    for (int e = g; e < cnt; e += 64) {
        int jj[8]; float wv8[8]; float4 v4[8];
        #pragma unroll
        for (int k = 0; k < 8; ++k) {
            int ee = e + 8 * k;
            bool ok = ee < cnt;
            jj[k]  = ok ? list[ee] : 0;
            wv8[k] = ok ? wl[ee]   : 0.f;
        }
        #pragma unroll
        for (int k = 0; k < 8; ++k) {
            int j = jj[k];
            v4[k] = (j < S_PAST) ? ((const float4*)(vbase + (size_t)j * DD))[dq] : vnew[dq];
        }
        #pragma unroll
        for (int k = 0; k < 8; ++k) {
            acc.x = fmaf(wv8[k], v4[k].x, acc.x);
            acc.y = fmaf(wv8[k], v4[k].y, acc.y);
            acc.z = fmaf(wv8[k], v4[k].z, acc.z);
            acc.w = fmaf(wv8[k], v4[k].w, acc.w);
        }
    }
    red[g][dq * 4 + 0] = acc.x; red[g][dq * 4 + 1] = acc.y;
    red[g][dq * 4 + 2] = acc.z; red[g][dq * 4 + 3] = acc.w;
    __syncthreads();
    if (tid < DD) {
        float s = 0.f;
        #pragma unroll
        for (int gg = 0; gg < 8; ++gg) s += red[gg][tid];
        ws[OFF_A + b * HQ * DD + h * DD + tid] = s * inv;
    }
}

// ---------------- Kernel 5: output GEMV, 8-deep float4 pipeline ----------------
__global__ __launch_bounds__(256) void k_out(const float* __restrict__ ws,
                                             const float* __restrict__ wo,
                                             float* __restrict__ wsp) {
    __shared__ float a[BB][64];
    const int tid = threadIdx.x;
    const int bx = blockIdx.x, ch = blockIdx.y;
    const int i0 = ch * 64;
    if (tid < BB * 64) {
        int b = tid >> 6, ii = tid & 63;
        a[b][ii] = ws[OFF_A + b * HQ * DD + i0 + ii];
    }
    __syncthreads();
    const int c4 = bx * 1024 + tid * 4;
    const float* wp = wo + (size_t)i0 * HID + c4;
    float4 a0 = {0,0,0,0}, a1 = {0,0,0,0}, a2 = {0,0,0,0}, a3 = {0,0,0,0};
    for (int ii = 0; ii < 64; ii += 8) {
        float4 wr[8];
        #pragma unroll
        for (int u = 0; u < 8; ++u)
            wr[u] = *(const float4*)(wp + (size_t)(ii + u) * HID);
        #pragma unroll
        for (int u = 0; u < 8; ++u) {
            float h0 = a[0][ii+u], h1 = a[1][ii+u], h2 = a[2][ii+u], h3 = a[3][ii+u];
            float4 w4 = wr[u];
            a0.x = fmaf(h0, w4.x, a0.x); a0.y = fmaf(h0, w4.y, a0.y); a0.z = fmaf(h0, w4.z, a0.z); a0.w = fmaf(h0, w4.w, a0.w);
            a1.x = fmaf(h1, w4.x, a1.x); a1.y = fmaf(h1, w4.y, a1.y); a1.z = fmaf(h1, w4.z, a1.z); a1.w = fmaf(h1, w4.w, a1.w);
            a2.x = fmaf(h2, w4.x, a2.x); a2.y = fmaf(h2, w4.y, a2.y); a2.z = fmaf(h2, w4.z, a2.z); a2.w = fmaf(h2, w4.w, a2.w);
            a3.x = fmaf(h3, w4.x, a3.x); a3.y = fmaf(h3, w4.y, a3.y); a3.z = fmaf(h3, w4.z, a3.z); a3.w = fmaf(h3, w4.w, a3.w);
        }
    }
    const int cq = bx * 256 + tid;
    ((float4*)(wsp + (size_t)(ch * 4 + 0) * HID))[cq] = a0;
    ((float4*)(wsp + (size_t)(ch * 4 + 1) * HID))[cq] = a1;
    ((float4*)(wsp + (size_t)(ch * 4 + 2) * HID))[cq] = a2;
    ((float4*)(wsp + (size_t)(ch * 4 + 3) * HID))[cq] = a3;
}

// ---------------- Kernel 6: reduce out partials -> d_out ----------------
__global__ __launch_bounds__(256) void k_out_red(const float* __restrict__ wsp,
                                                 float* __restrict__ out) {
    __shared__ float sh[2][BB][128];
    const int tid = threadIdx.x;
    const int i = tid & 127, half = tid >> 7;
    const int c = blockIdx.x * 128 + i;
    float s0 = 0.f, s1 = 0.f, s2 = 0.f, s3 = 0.f;
    for (int cb = 0; cb < 32; cb += 8) {
        float r[8][4];
        #pragma unroll
        for (int u = 0; u < 8; ++u) {
            const float* p = wsp + (size_t)((half * 32 + cb + u) * 4) * HID + c;
            r[u][0] = p[0]; r[u][1] = p[HID]; r[u][2] = p[2 * HID]; r[u][3] = p[3 * HID];
        }
        #pragma unroll
        for (int u = 0; u < 8; ++u) { s0 += r[u][0]; s1 += r[u][1]; s2 += r[u][2]; s3 += r[u][3]; }
    }
    sh[half][0][i] = s0; sh[half][1][i] = s1; sh[half][2][i] = s2; sh[half][3][i] = s3;
    __syncthreads();
    if (tid < 128) {
        #pragma unroll
        for (int b = 0; b < BB; ++b)
            out[b * HID + c] = sh[0][b][i] + sh[1][b][i];
    }
}

extern "C" void kernel_launch(void* const* d_in, const int* in_sizes, int n_in,
                              void* d_out, int out_size, void* d_ws, size_t ws_size,
                              hipStream_t stream) {
    const float* hidden = (const float*)d_in[0];
    const float* cosp   = (const float*)d_in[1];
    const float* sinp   = (const float*)d_in[2];
    const float* pk     = (const float*)d_in[3];
    const float* pv     = (const float*)d_in[4];
    const float* wq     = (const float*)d_in[5];
    const float* wk     = (const float*)d_in[6];
    const float* wv     = (const float*)d_in[7];
    const float* wo     = (const float*)d_in[8];
    float* out = (float*)d_out;
    float* ws  = (float*)d_ws;
    float* wsp = ws + OFF_P;

    k_qkv    <<<dim3(6, NCH1), 256, 0, stream>>>(hidden, wq, wk, wv, wsp);
    k_qkv_red<<<48,            256, 0, stream>>>(wsp, cosp, sinp, ws);
    k_scores <<<BB * HKV * 32, 256, 0, stream>>>(pk, ws);
    k_attn   <<<BB * HQ,       256, 0, stream>>>(pv, ws);
    k_out    <<<dim3(4, NCH2), 256, 0, stream>>>(ws, wo, wsp);
    k_out_red<<<32,            256, 0, stream>>>(wsp, out);
}